// Round 5
// baseline (126.394 us; speedup 1.0000x reference)
//
#include <hip/hip_runtime.h>
#include <hip/hip_bf16.h>

// PairwiseScore: B=2, N=256, E=512, H=150 (padded to 160)
// out[b,i,j] = (m[b,i] + m[b,j] + MLP3(g_i, g_j)) / 3
//
// Fold: hij + hj = sum_e (g_i[e]*W1c[e,h] + W1b[e,h]) * g_j[e]
// R8: register-occupancy attack. Measured law: unified VGPR+AGPR ~180/thr
// at acc=80 f32 => 2 waves/SIMD, no co-residence ever (R7: 2nd block never
// resident, 58.6us). Fix: 1024-thr block, 16 waves = 8 j-groups x 2 h-halves,
// each wave 5 ht x 2 jt => acc 40 f32 => ~100 regs => 4 waves/SIMD.
//  - A~ LDS-read volume UNCHANGED vs R0 (5 frags/kt/wave, 16 waves = 1280).
//  - GEMM2: h1 staged to freed 80KB stage as [j][160] bf16, XOR-swizzled
//    (^((j&3)<<4)); B-frags read full-k from LDS (h-split makes shfl
//    transform impossible). W2T A-frags direct from L2 (50KB hot).
//  - GEMM3: wave-pair partial scores reduced via 2KB LDS scorebuf.
//  - one-shot megas {8,8}, barrier graph A..G. No async W2TF staging.

typedef __attribute__((ext_vector_type(4))) float f32x4;
typedef __attribute__((ext_vector_type(4))) unsigned int u32x4;
typedef __attribute__((ext_vector_type(2))) unsigned int u32x2;
typedef __attribute__((ext_vector_type(8))) short short8;

#define NN 256
#define NE 512
#define NH 150
#define HP 160      // padded H
#define NKT 16      // NE/32 k-tiles for GEMM1
#define NHT 10      // HP/16 h-tiles
#define NS 5        // HP/32 k-steps for GEMM2
#define WHT 5       // h-tiles per wave (h-split)

// ---------- helpers ----------
__device__ __forceinline__ unsigned pk_bf16(float a, float b) {
  unsigned ua = __builtin_bit_cast(unsigned, a);
  unsigned ub = __builtin_bit_cast(unsigned, b);
  ua += 0x7fffu + ((ua >> 16) & 1u);
  ub += 0x7fffu + ((ub >> 16) & 1u);
  return (ua >> 16) | (ub & 0xffff0000u);
}
__device__ __forceinline__ float bf_lo(unsigned u) { return __builtin_bit_cast(float, u << 16); }
__device__ __forceinline__ float bf_hi(unsigned u) { return __builtin_bit_cast(float, u & 0xffff0000u); }

// ---------- prep: grid 365 x 256 (unchanged from R7 -- proven) ----------
__global__ __launch_bounds__(256) void prep_pack(
    const float* __restrict__ g, const float* __restrict__ W1,
    const float* __restrict__ W2,
    unsigned short* __restrict__ g_bf16, unsigned short* __restrict__ WaF,
    unsigned short* __restrict__ WbF, unsigned short* __restrict__ WcF,
    unsigned short* __restrict__ W2TF)
{
  __shared__ float tile[16][161];
  int bid = blockIdx.x, tid = threadIdx.x;
  if (bid < 256) {
    int t = bid * 256 + tid;
    f32x4 v = ((const f32x4*)g)[t];
    u32x2 o; o[0] = pk_bf16(v[0], v[1]); o[1] = pk_bf16(v[2], v[3]);
    ((u32x2*)g_bf16)[t] = o;
  } else if (bid < 352) {
    int bb = bid - 256;
    int mat = bb >> 5;
    int kt = (bb & 31) >> 1;
    int half = bb & 1;
    const float* __restrict__ Wm =
        W1 + ((size_t)mat * NE + (size_t)kt * 32 + (size_t)half * 16) * NH;
    for (int idx = tid; idx < 16 * NH; idx += 256) {
      int e = idx / NH, h = idx - e * NH;
      tile[e][h] = Wm[idx];
    }
    for (int idx = tid; idx < 16 * 10; idx += 256)
      tile[idx / 10][NH + (idx % 10)] = 0.f;
    __syncthreads();
    unsigned short* dst = (mat == 0) ? WaF : (mat == 1) ? WbF : WcF;
#pragma unroll
    for (int r = 0; r < 2; ++r) {
      int rr = tid + r * 256;
      if (rr < 320) {
        int chh = rr >> 5;
        int l = half * 32 + (rr & 31);
        int el = ((l >> 4) & 1) * 8;
        int h = chh * 16 + (l & 15);
        u32x4 o;
#pragma unroll
        for (int q = 0; q < 4; ++q)
          o[q] = pk_bf16(tile[el + 2 * q][h], tile[el + 2 * q + 1][h]);
        ((u32x4*)dst)[kt * 640 + chh * 64 + l] = o;
      }
    }
  } else {
    int row = (bid - 352) * 256 + tid;
    if (row < 3200) {
      int s = row / 640; int rem = row - s * 640;
      int l = rem & 63; int chh = rem >> 6;
      int k = s * 32 + (l >> 4) * 8;
      int hp = chh * 16 + (l & 15);
      u32x4 o;
#pragma unroll
      for (int q = 0; q < 4; ++q) {
        int k0 = k + 2 * q, k1 = k0 + 1;
        float v0 = (k0 < NH && hp < NH) ? W2[(size_t)k0 * NH + hp] : 0.f;
        float v1 = (k1 < NH && hp < NH) ? W2[(size_t)k1 * NH + hp] : 0.f;
        o[q] = pk_bf16(v0, v1);
      }
      ((u32x4*)W2TF)[row] = o;
    }
  }
}

// ---------- main fused kernel: 1024 threads, one block per (b,i) ----------
__global__ __launch_bounds__(1024) void pair_main(
    const float* __restrict__ mention, const float* __restrict__ b1,
    const float* __restrict__ b2, const float* __restrict__ W3,
    const float* __restrict__ b3,
    const unsigned short* __restrict__ g_bf16,
    const unsigned short* __restrict__ WaF,
    const unsigned short* __restrict__ WbF, const unsigned short* __restrict__ WcF,
    const unsigned short* __restrict__ W2TF,
    float* __restrict__ out)
{
  __shared__ unsigned int stage[8 * NHT * 64 * 4];  // 80 KB: A~ megas, then h1
  __shared__ unsigned int gi_lds[NE / 2];           // g_i bf16 (1 KB)
  __shared__ alignas(16) float bias1[HP];           // b1 + hi
  __shared__ alignas(16) float bias2[HP];
  __shared__ alignas(16) float w3s[HP];
  __shared__ float scorebuf[8][2][32];              // wave-pair GEMM3 partials

  const int tid = threadIdx.x;
  const int bi = blockIdx.x;
  const int b = bi >> 8, i = bi & 255;
  const int lane = tid & 63, wave = tid >> 6;       // 16 waves
  const int c16 = lane & 15, quad = lane >> 4;
  const int jg = wave >> 1, hh = wave & 1;          // j-group 0..7, h-half 0..1

  // ---- phase 0: per-block constants into LDS ----
  {
    const u32x4* grow = (const u32x4*)(g_bf16 + (size_t)(b * NN + i) * NE);
    if (tid < 64) ((u32x4*)gi_lds)[tid] = grow[tid];
    if (tid >= 128 && tid < 128 + HP) {
      int h = tid - 128;
      bias1[h] = (h < NH) ? b1[h] : 0.f;
      bias2[h] = (h < NH) ? b2[h] : 0.f;
      w3s[h]   = (h < NH) ? W3[h] : 0.f;
    }
  }
  __syncthreads();   // barrier A

  // ---- builder for one 8-kt mega-tile: exactly 5 rows/thread (5120 rows) ----
  auto build_mega = [&](int mega) {
#pragma unroll
    for (int r = 0; r < 5; ++r) {
      int v = tid + r * 1024;                // 0..5119
      int ktl = v / 640; int rem = v - ktl * 640;
      int l = rem & 63;
      int ktg = mega * 8 + ktl;
      int gidx = ktg * 640 + (rem >> 6) * 64 + l;
      u32x4 wb = ((const u32x4*)WbF)[gidx];
      u32x4 wc = ((const u32x4*)WcF)[gidx];
      u32x4 gi = ((const u32x4*)gi_lds)[ktg * 4 + (l >> 4)];
      u32x4 o;
#pragma unroll
      for (int q = 0; q < 4; ++q) {
        float lo = bf_lo(gi[q]) * bf_lo(wc[q]) + bf_lo(wb[q]);
        float hi = bf_hi(gi[q]) * bf_hi(wc[q]) + bf_hi(wb[q]);
        o[q] = pk_bf16(lo, hi);
      }
      ((u32x4*)stage)[v] = o;
    }
  };

  // ---- mega 0 build; waves 0-9 compute hi (one ht each) via mini-MFMA ----
  build_mega(0);
  if (wave < NHT) {
    f32x4 ah = {};
#pragma unroll
    for (int kt = 0; kt < NKT; ++kt) {
      short8 bbc = __builtin_bit_cast(short8, ((const u32x4*)gi_lds)[kt * 4 + quad]);
      short8 a0 = __builtin_bit_cast(short8,
          ((const u32x4*)WaF)[(kt * NHT + wave) * 64 + lane]);
      ah = __builtin_amdgcn_mfma_f32_16x16x32_bf16(a0, bbc, ah, 0, 0, 0);
    }
    if (c16 == 0) {
#pragma unroll
      for (int r = 0; r < 4; ++r)
        bias1[wave * 16 + quad * 4 + r] += ah[r];
    }
  }
  __syncthreads();   // barrier B: mega-0 A~ + bias1 ready

  // ---- phase 1: D1[h][j] = A~ * g_j  (wave: ht in [5hh,5hh+5), j in jg*32+[0,32)) ----
  f32x4 acc1[WHT][2] = {};
  const u32x4* gB = (const u32x4*)g_bf16;
  const size_t gidx0 = (size_t)(b * NN + jg * 32 + c16) * 64 + quad;  // u32x4 units

  auto gemm1_phase = [&](int ktbase) {
#pragma unroll 1
    for (int ktl = 0; ktl < 8; ++ktl) {
      int ktg = ktbase + ktl;
      short8 bf0 = __builtin_bit_cast(short8, gB[gidx0 + (size_t)ktg * 4]);
      short8 bf1 = __builtin_bit_cast(short8, gB[gidx0 + 16 * 64 + (size_t)ktg * 4]);
      const u32x4* As = (const u32x4*)stage + ktl * (NHT * 64);
#pragma unroll
      for (int ht = 0; ht < WHT; ++ht) {
        short8 af = __builtin_bit_cast(short8, As[(WHT * hh + ht) * 64 + lane]);
        acc1[ht][0] = __builtin_amdgcn_mfma_f32_16x16x32_bf16(af, bf0, acc1[ht][0], 0, 0, 0);
        acc1[ht][1] = __builtin_amdgcn_mfma_f32_16x16x32_bf16(af, bf1, acc1[ht][1], 0, 0, 0);
      }
    }
  };

  gemm1_phase(0);
  __syncthreads();   // barrier C: mega-0 reads done
  build_mega(1);
  __syncthreads();   // barrier D: mega-1 ready
  gemm1_phase(8);
  __syncthreads();   // barrier E: all stage reads done -> stage becomes h1

  // ---- epilogue 1: h1 = relu(D1 + hi + b1) -> bf16 into stage as [j][160],
  //      byte = j*320 + ((h*2) ^ ((j&3)<<4))  (XOR keeps 8B/16B alignment) ----
  {
    char* h1 = (char*)stage;
#pragma unroll
    for (int ht = 0; ht < WHT; ++ht) {
      int ht_g = WHT * hh + ht;
      f32x4 bv = *(const f32x4*)(bias1 + ht_g * 16 + quad * 4);
#pragma unroll
      for (int jt = 0; jt < 2; ++jt) {
        int j = jg * 32 + jt * 16 + c16;
        f32x4 v = acc1[ht][jt];
        float r0 = fmaxf(v[0] + bv[0], 0.f);
        float r1 = fmaxf(v[1] + bv[1], 0.f);
        float r2 = fmaxf(v[2] + bv[2], 0.f);
        float r3 = fmaxf(v[3] + bv[3], 0.f);
        u32x2 o; o[0] = pk_bf16(r0, r1); o[1] = pk_bf16(r2, r3);
        int hb = (ht_g * 16 + quad * 4) * 2;          // 32ht_g + 8q, 8B-aligned
        *(u32x2*)(h1 + j * 320 + (hb ^ ((j & 3) << 4))) = o;
      }
    }
  }
  __syncthreads();   // barrier F: h1 complete

  // ---- phase 2: D2[h'][j] = W2^T * h1 ; B-frags full-k from LDS h1 ----
  f32x4 acc2[WHT][2] = {};
  {
    const char* h1 = (const char*)stage;
    const u32x4* A2g = (const u32x4*)W2TF;
#pragma unroll
    for (int s = 0; s < NS; ++s) {
      short8 b2f[2];
#pragma unroll
      for (int jt = 0; jt < 2; ++jt) {
        int j = jg * 32 + jt * 16 + c16;
        int kb = s * 64 + quad * 16;                  // 16B-aligned
        u32x4 t = *(const u32x4*)(h1 + j * 320 + (kb ^ ((j & 3) << 4)));
        b2f[jt] = __builtin_bit_cast(short8, t);
      }
#pragma unroll
      for (int ht = 0; ht < WHT; ++ht) {
        short8 af = __builtin_bit_cast(short8,
            A2g[(s * NHT + WHT * hh + ht) * 64 + lane]);
        acc2[ht][0] = __builtin_amdgcn_mfma_f32_16x16x32_bf16(af, b2f[0], acc2[ht][0], 0, 0, 0);
        acc2[ht][1] = __builtin_amdgcn_mfma_f32_16x16x32_bf16(af, b2f[1], acc2[ht][1], 0, 0, 0);
      }
    }
  }

  // ---- epilogue 2 + GEMM3: partial over this wave's 5 ht' ----
  float part0 = 0.f, part1 = 0.f;
#pragma unroll
  for (int ht = 0; ht < WHT; ++ht) {
    int ht_g = WHT * hh + ht;
    f32x4 bv = *(const f32x4*)(bias2 + ht_g * 16 + quad * 4);
    f32x4 wv = *(const f32x4*)(w3s + ht_g * 16 + quad * 4);
    f32x4 v0 = acc2[ht][0], v1 = acc2[ht][1];
#pragma unroll
    for (int r = 0; r < 4; ++r) {
      part0 += fmaxf(v0[r] + bv[r], 0.f) * wv[r];
      part1 += fmaxf(v1[r] + bv[r], 0.f) * wv[r];
    }
  }
  part0 += __shfl_xor(part0, 16); part0 += __shfl_xor(part0, 32);
  part1 += __shfl_xor(part1, 16); part1 += __shfl_xor(part1, 32);

  if (quad == 0) {
    scorebuf[jg][hh][c16]      = part0;
    scorebuf[jg][hh][16 + c16] = part1;
  }
  __syncthreads();   // barrier G: both halves' partials visible

  if (hh == 0 && quad == 0) {
    const float mi = mention[b * NN + i];
    const float b3v = b3[0];
    int j0 = jg * 32 + c16;
    int j1 = j0 + 16;
    float s0 = part0 + scorebuf[jg][1][c16];
    float s1 = part1 + scorebuf[jg][1][16 + c16];
    float mj0 = mention[b * NN + j0];
    float mj1 = mention[b * NN + j1];
    out[((size_t)(b * NN + i)) * NN + j0] = (mi + mj0 + s0 + b3v) * (1.f / 3.f);
    out[((size_t)(b * NN + i)) * NN + j1] = (mi + mj1 + s1 + b3v) * (1.f / 3.f);
  }
}

// ---------- launch ----------
extern "C" void kernel_launch(void* const* d_in, const int* in_sizes, int n_in,
                              void* d_out, int out_size, void* d_ws, size_t ws_size,
                              hipStream_t stream) {
  const float* g  = (const float*)d_in[0];
  const float* m  = (const float*)d_in[1];
  const float* W1 = (const float*)d_in[2];
  const float* b1 = (const float*)d_in[3];
  const float* W2 = (const float*)d_in[4];
  const float* b2 = (const float*)d_in[5];
  const float* W3 = (const float*)d_in[6];
  const float* b3 = (const float*)d_in[7];
  float* out = (float*)d_out;

  char* ws = (char*)d_ws;
  unsigned short* g_bf16 = (unsigned short*)(ws);              // 524288 B
  unsigned short* WaF    = (unsigned short*)(ws + 524288);     // 163840 B
  unsigned short* WbF    = (unsigned short*)(ws + 688128);     // 163840 B
  unsigned short* WcF    = (unsigned short*)(ws + 851968);     // 163840 B
  unsigned short* W2TF   = (unsigned short*)(ws + 1015808);    //  51200 B (total ~1.02 MB)

  prep_pack<<<365, 256, 0, stream>>>(g, W1, W2, g_bf16, WaF, WbF, WcF, W2TF);
  pair_main<<<512, 1024, 0, stream>>>(m, b1, b2, W3, b3, g_bf16, WaF, WbF, WcF, W2TF, out);
}